// Round 8
// baseline (194.779 us; speedup 1.0000x reference)
//
#include <hip/hip_runtime.h>
#include <hip/hip_bf16.h>

// AGREE fused, round 15. R7 post-mortem: MFMA path ran (VALUBusy 55->37%,
// FETCH 52->30.8MB) but dur 46.7->44.3us only. Four different structures all
// land 43-48us: latency-bound, waves stalled ~87% of lifetime, ~63% of issue
// slots idle, stalls phase-correlated across waves.
// This round: TWO independent groups per wave. The second group's dataflow
// fills the first group's memory-wait windows (in-order wave, but loads of
// both groups issue before either's dependent wait; compiler interleaves the
// independent chains). Group concurrency/CU ~11 -> ~24 at constant traffic.
// 64-thread blocks (1 wave): barriers wave-local, blocks retire alone.
// Static-indexed arrays via #pragma unroll phase loops (scratch rule #20).
// __launch_bounds__(64,3) -> VGPR cap ~170 (est ~150 unified, no spill).
// Numerics per group identical to verified R7. Probe unchanged.

__global__ void AGREE_12773232738622_probe(
    const void* member_mask,            // [8192, 50] unknown element width
    const void* user_table,             // [100000, 64] f32 or bf16
    int* ws)                            // ws[0]=width (1/2/4/8), ws[1]=isf32, ws[2]=done
{
    if (ws[2] == 0x5AFE0001) return;    // sticky: skip on graph replays if ws persists

    const int lane = threadIdx.x;       // 64 lanes
    const int wi = lane >> 4;           // candidate width index 0..3 (W = 1<<wi)
    const int r  = lane & 15;           // sample row 0..15 for this width

    int len = 0, ok = 1, prev = 1;
    for (int m = 0; m < 50; ++m) {
        long e = 50L * r + m;
        int nz;
        if (wi == 0)      nz = (((const unsigned char*)member_mask)[e] != 0);
        else if (wi == 1) nz = (((const unsigned short*)member_mask)[e] != 0);
        else if (wi == 2) nz = (((const unsigned int*)member_mask)[e] != 0u);
        else {
            const unsigned int* p = (const unsigned int*)member_mask;
            nz = ((p[2 * e] | p[2 * e + 1]) != 0u);
        }
        if (nz && !prev) ok = 0;        // gap -> not a prefix -> wrong width
        if (nz) len = len + 1;
        prev = nz;
    }
    if (len == 0) ok = 0;

    ok = ok & __shfl_xor(ok, 1);
    ok = ok & __shfl_xor(ok, 2);
    ok = ok & __shfl_xor(ok, 4);
    ok = ok & __shfl_xor(ok, 8);
    int mx = len;
    mx = max(mx, __shfl_xor(mx, 1));
    mx = max(mx, __shfl_xor(mx, 2));
    mx = max(mx, __shfl_xor(mx, 4));
    mx = max(mx, __shfl_xor(mx, 8));

    int o0 = __shfl(ok, 0),  o1 = __shfl(ok, 16), o2 = __shfl(ok, 32), o3 = __shfl(ok, 48);
    int L0 = __shfl(mx, 0),  L1 = __shfl(mx, 16), L2 = __shfl(mx, 32), L3 = __shfl(mx, 48);

    float v = __bfloat162float(((const __hip_bfloat16*)user_table)[lane]);
    float a = (v < 0.0f) ? -v : v;
    int huge = (!(a < 4.0f)) ? 1 : 0;
    unsigned long long hb = __ballot(huge);
    int hcnt = __popcll(hb);

    if (lane == 0) {
        int bestW = 1, bestLen = -1;
        if (o0 && L0 > bestLen) { bestLen = L0; bestW = 1; }
        if (o1 && L1 > bestLen) { bestLen = L1; bestW = 2; }
        if (o2 && L2 > bestLen) { bestLen = L2; bestW = 4; }
        if (o3 && L3 > bestLen) { bestLen = L3; bestW = 8; }
        ws[0] = bestW;
        ws[1] = (hcnt >= 8) ? 1 : 0;
        ws[2] = 0x5AFE0001;
    }
}

__global__ __launch_bounds__(64, 3) void AGREE_12773232738622_kernel(
    const int* member_idx,              // [8192, 50] int32
    const void* member_mask,            // [8192, 50] width in ws[0]
    const int* item_inputs,             // [8192] int32
    const void* user_table,             // [100000, 64]
    const void* item_table,             // [50000, 64]
    const void* att_w1,                 // [128, 16]
    const void* att_b1,                 // [16]
    const void* att_w2,                 // [16, 1]
    const void* att_b2,                 // [1]
    const void* pred_w1,                // [192, 8]
    const void* pred_b1,                // [8]
    const void* pred_w2,                // [8, 1]
    const void* pred_b2,                // [1]
    void* out,                          // [8192] (dtype follows ws[1])
    const int* ws)
{
    using s16x8 = __attribute__((ext_vector_type(8))) short;   // 8 bf16 raw
    using bf16x8 = __attribute__((ext_vector_type(8))) __bf16;
    using f32x4 = __attribute__((ext_vector_type(4))) float;

    __shared__ float s_l[2][64];        // logit transpose scratch (per group)
    __shared__ float s_g[2][64];        // pooled-g transpose scratch

    const int lane = threadIdx.x;       // 64 lanes, one wave per block
    const int mode = ws[0];
    const int isf  = ws[1];

    int bb[2];
    bb[0] = blockIdx.x * 2;
    bb[1] = blockIdx.x * 2 + 1;

    // ---- masks (both groups), prefix via ballot ----
    int validv[2], lenv[2];
    #pragma unroll
    for (int g = 0; g < 2; ++g) {
        int valid = 0;
        if (lane < 50) {
            long e0 = 50L * bb[g] + lane;
            if (mode == 1)      valid = (((const unsigned char*)member_mask)[e0] != 0);
            else if (mode == 2) valid = (((const unsigned short*)member_mask)[e0] != 0);
            else if (mode == 4) valid = (((const unsigned int*)member_mask)[e0] != 0u);
            else {
                const unsigned int* p = (const unsigned int*)member_mask;
                valid = ((p[2 * e0] | p[2 * e0 + 1]) != 0u);
            }
        }
        validv[g] = valid;
        unsigned long long vm = __ballot(valid);
        int len = __popcll(vm);
        if (len < 1)  len = 1;
        if (len > 50) len = 50;
        lenv[g] = len;
    }

    int item_id[2], idxv[2];
    #pragma unroll
    for (int g = 0; g < 2; ++g) {
        item_id[g] = item_inputs[bb[g]];
        idxv[g] = 0;
        if (lane < 50) idxv[g] = member_idx[bb[g] * 50 + lane];
    }

    if (!isf) {
        // ================= bf16 MFMA path, two groups interleaved =================
        const unsigned short* utp = (const unsigned short*)user_table;
        const unsigned short* w1p = (const unsigned short*)att_w1;

        float itemv[2];
        #pragma unroll
        for (int g = 0; g < 2; ++g)
            itemv[g] = __uint_as_float(
                (unsigned int)((const unsigned short*)item_table)[item_id[g] * 64 + lane] << 16);

        // ---- B fragments (shared): bfrag[kc] lane holds w1[kc*32+(l>>4)*8+j][l&15] ----
        const int kn = lane & 15;       // N index (hidden k)
        const int kg = lane >> 4;       // K group
        s16x8 bfrag[4];
        #pragma unroll
        for (int kc = 0; kc < 4; ++kc) {
            #pragma unroll
            for (int j = 0; j < 8; ++j)
                bfrag[kc][j] = (short)w1p[(kc * 32 + kg * 8 + j) * 16 + kn];
        }

        // ---- A fragments, both groups: all 20 scattered loads issue up front ----
        s16x8 afrag[2][4][2];
        s16x8 ifr[2][2];
        #pragma unroll
        for (int g = 0; g < 2; ++g) {
            #pragma unroll
            for (int t = 0; t < 4; ++t) {
                int m  = t * 16 + (lane & 15);
                int mc = (m < 50) ? m : 0;              // pad rows -> member 0 (masked)
                int id = __shfl(idxv[g], mc);
                const unsigned short* rp = utp + (long)id * 64 + kg * 8;
                afrag[g][t][0] = *(const s16x8*)(rp);
                afrag[g][t][1] = *(const s16x8*)(rp + 32);
            }
            const unsigned short* ipp = (const unsigned short*)item_table
                                      + (long)item_id[g] * 64 + kg * 8;
            ifr[g][0] = *(const s16x8*)(ipp);
            ifr[g][1] = *(const s16x8*)(ipp + 32);
        }

        // ---- 32 MFMA: h for both groups ----
        f32x4 acc[2][4];
        #pragma unroll
        for (int g = 0; g < 2; ++g)
            #pragma unroll
            for (int t = 0; t < 4; ++t) acc[g][t] = f32x4{0.0f, 0.0f, 0.0f, 0.0f};
        #pragma unroll
        for (int g = 0; g < 2; ++g) {
            #pragma unroll
            for (int t = 0; t < 4; ++t) {
                acc[g][t] = __builtin_amdgcn_mfma_f32_16x16x32_bf16(
                    __builtin_bit_cast(bf16x8, afrag[g][t][0]), __builtin_bit_cast(bf16x8, bfrag[0]), acc[g][t], 0, 0, 0);
                acc[g][t] = __builtin_amdgcn_mfma_f32_16x16x32_bf16(
                    __builtin_bit_cast(bf16x8, afrag[g][t][1]), __builtin_bit_cast(bf16x8, bfrag[1]), acc[g][t], 0, 0, 0);
                acc[g][t] = __builtin_amdgcn_mfma_f32_16x16x32_bf16(
                    __builtin_bit_cast(bf16x8, ifr[g][0]),      __builtin_bit_cast(bf16x8, bfrag[2]), acc[g][t], 0, 0, 0);
                acc[g][t] = __builtin_amdgcn_mfma_f32_16x16x32_bf16(
                    __builtin_bit_cast(bf16x8, ifr[g][1]),      __builtin_bit_cast(bf16x8, bfrag[3]), acc[g][t], 0, 0, 0);
            }
        }

        // ---- epilogue: logit_m = b2 + sum_k relu(h+b1)*w2 ----
        const float b1v = __uint_as_float((unsigned int)((const unsigned short*)att_b1)[kn] << 16);
        const float w2v = __uint_as_float((unsigned int)((const unsigned short*)att_w2)[kn] << 16);
        const float b2v = __uint_as_float((unsigned int)((const unsigned short*)att_b2)[0] << 16);
        #pragma unroll
        for (int g = 0; g < 2; ++g) {
            #pragma unroll
            for (int t = 0; t < 4; ++t) {
                #pragma unroll
                for (int r = 0; r < 4; ++r) {
                    float v = fmaxf(acc[g][t][r] + b1v, 0.0f) * w2v;
                    v += __shfl_xor(v, 1);
                    v += __shfl_xor(v, 2);
                    v += __shfl_xor(v, 4);
                    v += __shfl_xor(v, 8);
                    // C/D layout: member m = t*16 + (lane>>4)*4 + r
                    if ((lane & 15) == 0) s_l[g][t * 16 + (lane >> 4) * 4 + r] = v;
                }
            }
        }
        __syncthreads();                // logits visible across lanes (1 wave: cheap)

        // ---- masked softmax, both groups (independent chains) ----
        float wnorm[2];
        #pragma unroll
        for (int g = 0; g < 2; ++g) {
            float lg = (lane < 50) ? s_l[g][lane] : 0.0f;
            float x = validv[g] ? (lg + b2v) : -3.0e38f;
            float mxv = x;
            mxv = fmaxf(mxv, __shfl_xor(mxv, 1));
            mxv = fmaxf(mxv, __shfl_xor(mxv, 2));
            mxv = fmaxf(mxv, __shfl_xor(mxv, 4));
            mxv = fmaxf(mxv, __shfl_xor(mxv, 8));
            mxv = fmaxf(mxv, __shfl_xor(mxv, 16));
            mxv = fmaxf(mxv, __shfl_xor(mxv, 32));
            float p = validv[g] ? expf(x - mxv) : 0.0f;
            float sum = p;
            sum += __shfl_xor(sum, 1);
            sum += __shfl_xor(sum, 2);
            sum += __shfl_xor(sum, 4);
            sum += __shfl_xor(sum, 8);
            sum += __shfl_xor(sum, 16);
            sum += __shfl_xor(sum, 32);
            if (sum > 0.0f) wnorm[g] = p * (1.0f / sum);
            else            wnorm[g] = (lane == 0) ? 1.0f : 0.0f;  // NaN guard
        }

        // ---- pooling from the A-fragments in registers, both groups ----
        #pragma unroll
        for (int g = 0; g < 2; ++g) {
            float pg[2][8];
            #pragma unroll
            for (int ks = 0; ks < 2; ++ks)
                #pragma unroll
                for (int j = 0; j < 8; ++j) pg[ks][j] = 0.0f;
            #pragma unroll
            for (int t = 0; t < 4; ++t) {
                float wv = __shfl(wnorm[g], t * 16 + (lane & 15));  // 0 for pads
                #pragma unroll
                for (int ks = 0; ks < 2; ++ks) {
                    #pragma unroll
                    for (int j = 0; j < 8; ++j) {
                        float e = __uint_as_float(
                            (unsigned int)(unsigned short)afrag[g][t][ks][j] << 16);
                        pg[ks][j] += wv * e;
                    }
                }
            }
            #pragma unroll
            for (int ks = 0; ks < 2; ++ks) {
                #pragma unroll
                for (int j = 0; j < 8; ++j) {
                    float v = pg[ks][j];
                    v += __shfl_xor(v, 1);
                    v += __shfl_xor(v, 2);
                    v += __shfl_xor(v, 4);
                    v += __shfl_xor(v, 8);
                    pg[ks][j] = v;
                }
            }
            if ((lane & 15) == 0) {
                #pragma unroll
                for (int ks = 0; ks < 2; ++ks)
                    #pragma unroll
                    for (int j = 0; j < 8; ++j)
                        s_g[g][ks * 32 + (lane >> 4) * 8 + j] = pg[ks][j];
            }
        }
        __syncthreads();                // pooled g visible, lane = dim

        // ---- prediction MLP, weights unpacked once, both groups ----
        const uint4* pw4 = (const uint4*)pred_w1;     // row r = pw4[r] (8 bf16 = 16B)
        uint4 A = pw4[lane];
        uint4 Bv = pw4[64 + lane];
        uint4 C = pw4[128 + lane];
        float ea[8], eb[8], ec[8];
        ea[0] = __uint_as_float(A.x << 16);  ea[1] = __uint_as_float(A.x & 0xFFFF0000u);
        ea[2] = __uint_as_float(A.y << 16);  ea[3] = __uint_as_float(A.y & 0xFFFF0000u);
        ea[4] = __uint_as_float(A.z << 16);  ea[5] = __uint_as_float(A.z & 0xFFFF0000u);
        ea[6] = __uint_as_float(A.w << 16);  ea[7] = __uint_as_float(A.w & 0xFFFF0000u);
        eb[0] = __uint_as_float(Bv.x << 16); eb[1] = __uint_as_float(Bv.x & 0xFFFF0000u);
        eb[2] = __uint_as_float(Bv.y << 16); eb[3] = __uint_as_float(Bv.y & 0xFFFF0000u);
        eb[4] = __uint_as_float(Bv.z << 16); eb[5] = __uint_as_float(Bv.z & 0xFFFF0000u);
        eb[6] = __uint_as_float(Bv.w << 16); eb[7] = __uint_as_float(Bv.w & 0xFFFF0000u);
        ec[0] = __uint_as_float(C.x << 16);  ec[1] = __uint_as_float(C.x & 0xFFFF0000u);
        ec[2] = __uint_as_float(C.y << 16);  ec[3] = __uint_as_float(C.y & 0xFFFF0000u);
        ec[4] = __uint_as_float(C.z << 16);  ec[5] = __uint_as_float(C.z & 0xFFFF0000u);
        ec[6] = __uint_as_float(C.w << 16);  ec[7] = __uint_as_float(C.w & 0xFFFF0000u);

        #pragma unroll
        for (int g = 0; g < 2; ++g) {
            const float gv = s_g[g][lane];
            const float gi = gv * itemv[g];
            float p8[8];
            #pragma unroll
            for (int k2 = 0; k2 < 8; ++k2)
                p8[k2] = gi * ea[k2] + gv * eb[k2] + itemv[g] * ec[k2];
            #pragma unroll
            for (int k2 = 0; k2 < 8; ++k2) {
                float v = p8[k2];
                v += __shfl_xor(v, 1);
                v += __shfl_xor(v, 2);
                v += __shfl_xor(v, 4);
                v += __shfl_xor(v, 8);
                v += __shfl_xor(v, 16);
                v += __shfl_xor(v, 32);
                p8[k2] = v;
            }
            if (lane == 0) {
                float z = __uint_as_float((unsigned int)((const unsigned short*)pred_b2)[0] << 16);
                for (int k2 = 0; k2 < 8; ++k2) {
                    float bb2 = __uint_as_float((unsigned int)((const unsigned short*)pred_b1)[k2] << 16);
                    float ww  = __uint_as_float((unsigned int)((const unsigned short*)pred_w2)[k2] << 16);
                    float hh = p8[k2] + bb2;
                    if (hh < 0.0f) hh = 0.0f;
                    z += hh * ww;
                }
                float y = 1.0f / (1.0f + expf(-z));
                ((__hip_bfloat16*)out)[bb[g]] = __float2bfloat16(y);
            }
        }
    } else {
        // ================= f32 fallback (R7 verified structure, per group) =======
        for (int gsel = 0; gsel < 2; ++gsel) {
            const int b = bb[gsel];
            const int valid = validv[gsel];
            const int len   = lenv[gsel];
            const int idxg  = idxv[gsel];
            const float itemv = ((const float*)item_table)[item_id[gsel] * 64 + lane];

            float part;
            {
                const int kk = lane & 15;
                const int c  = lane >> 4;
                part = (c == 0) ? ((const float*)att_b1)[kk] : 0.0f;
                for (int t = 0; t < 16; ++t) {
                    int f = c * 16 + t;
                    float iv = __shfl(itemv, f);
                    part += iv * ((const float*)att_w1)[(64 + f) * 16 + kk];
                }
                part += __shfl_xor(part, 16);
                part += __shfl_xor(part, 32);
            }
            float h[16];
            #pragma unroll
            for (int k = 0; k < 16; ++k) h[k] = __shfl(part, k);

            if (lane < len) {
                const float* rp = (const float*)user_table + (long)idxg * 64;
                const float* w1 = (const float*)att_w1;
                #pragma unroll 4
                for (int c = 0; c < 16; ++c) {
                    float4 v = ((const float4*)rp)[c];
                    #pragma unroll
                    for (int k = 0; k < 16; ++k) {
                        h[k] += v.x * w1[(c * 4 + 0) * 16 + k];
                        h[k] += v.y * w1[(c * 4 + 1) * 16 + k];
                        h[k] += v.z * w1[(c * 4 + 2) * 16 + k];
                        h[k] += v.w * w1[(c * 4 + 3) * 16 + k];
                    }
                }
            }

            float lg = ((const float*)att_b2)[0];
            #pragma unroll
            for (int k = 0; k < 16; ++k)
                lg += fmaxf(h[k], 0.0f) * ((const float*)att_w2)[k];

            float x = valid ? lg : -3.0e38f;
            float mxv = x;
            mxv = fmaxf(mxv, __shfl_xor(mxv, 1));
            mxv = fmaxf(mxv, __shfl_xor(mxv, 2));
            mxv = fmaxf(mxv, __shfl_xor(mxv, 4));
            mxv = fmaxf(mxv, __shfl_xor(mxv, 8));
            mxv = fmaxf(mxv, __shfl_xor(mxv, 16));
            mxv = fmaxf(mxv, __shfl_xor(mxv, 32));
            float p = valid ? expf(x - mxv) : 0.0f;
            float sum = p;
            sum += __shfl_xor(sum, 1);
            sum += __shfl_xor(sum, 2);
            sum += __shfl_xor(sum, 4);
            sum += __shfl_xor(sum, 8);
            sum += __shfl_xor(sum, 16);
            sum += __shfl_xor(sum, 32);
            float wnorm;
            if (sum > 0.0f) wnorm = p * (1.0f / sum);
            else            wnorm = (lane == 0) ? 1.0f : 0.0f;

            float g = 0.0f;
            const float* ut = (const float*)user_table;
            for (int m = 0; m < len; ++m) {
                int idm  = __shfl(idxg, m);
                float wv = __shfl(wnorm, m);
                g += wv * ut[(long)idm * 64 + lane];
            }

            const float gi = g * itemv;
            const float4* pw4 = (const float4*)pred_w1;
            float4 a0 = pw4[lane * 2],         a1 = pw4[lane * 2 + 1];
            float4 b0 = pw4[(64 + lane) * 2],  b1 = pw4[(64 + lane) * 2 + 1];
            float4 c0 = pw4[(128 + lane) * 2], c1 = pw4[(128 + lane) * 2 + 1];
            float p8[8];
            p8[0] = gi * a0.x + g * b0.x + itemv * c0.x;
            p8[1] = gi * a0.y + g * b0.y + itemv * c0.y;
            p8[2] = gi * a0.z + g * b0.z + itemv * c0.z;
            p8[3] = gi * a0.w + g * b0.w + itemv * c0.w;
            p8[4] = gi * a1.x + g * b1.x + itemv * c1.x;
            p8[5] = gi * a1.y + g * b1.y + itemv * c1.y;
            p8[6] = gi * a1.z + g * b1.z + itemv * c1.z;
            p8[7] = gi * a1.w + g * b1.w + itemv * c1.w;
            #pragma unroll
            for (int k2 = 0; k2 < 8; ++k2) {
                float v = p8[k2];
                v += __shfl_xor(v, 1);
                v += __shfl_xor(v, 2);
                v += __shfl_xor(v, 4);
                v += __shfl_xor(v, 8);
                v += __shfl_xor(v, 16);
                v += __shfl_xor(v, 32);
                p8[k2] = v;
            }
            if (lane == 0) {
                float z = ((const float*)pred_b2)[0];
                for (int k2 = 0; k2 < 8; ++k2) {
                    float hh = p8[k2] + ((const float*)pred_b1)[k2];
                    if (hh < 0.0f) hh = 0.0f;
                    z += hh * ((const float*)pred_w2)[k2];
                }
                float y = 1.0f / (1.0f + expf(-z));
                ((float*)out)[b] = y;
            }
        }
    }
}

extern "C" void kernel_launch(void* const* d_in, const int* in_sizes, int n_in,
                              void* d_out, int out_size, void* d_ws, size_t ws_size,
                              hipStream_t stream) {
    (void)in_sizes; (void)n_in; (void)out_size; (void)ws_size;
    AGREE_12773232738622_probe<<<1, 64, 0, stream>>>(
        d_in[1], d_in[3], (int*)d_ws);
    AGREE_12773232738622_kernel<<<4096, 64, 0, stream>>>(
        (const int*)d_in[0],
        d_in[1],
        (const int*)d_in[2],
        d_in[3],
        d_in[4],
        d_in[5],
        d_in[6],
        d_in[7],
        d_in[8],
        d_in[9],
        d_in[10],
        d_in[11],
        d_in[12],
        d_out,
        (const int*)d_ws);
}

// Round 9
// 160.309 us; speedup vs baseline: 1.2150x; 1.2150x over previous
//
#include <hip/hip_runtime.h>
#include <hip/hip_bf16.h>

// AGREE fused, round 16. R8 post-mortem: 2-group ILP regressed (44->79us,
// VGPR stuck at 72 => groups serialized by regalloc). Reverted to R7 base.
// New theory for the invariant ~44us across 5 structures: all share ~190
// __shfl_xor per row; shfl = ds_bpermute = LDS-pipe op (1 pipe/CU shared by
// 4 SIMDs). 8192 waves x 190 / 256 CU x ~4-8cy = 10-20us of LDS-pipe
// serialization + ~60cy dep-latency per tree stage. BANK_CONFLICT=0 fits
// (bpermute occupies, never conflicts).
// This round: all butterfly reductions -> DPP on the VALU (zero LDS pipe):
//   xor1 = quad_perm[1,0,3,2]=0xB1, xor2 = quad_perm[2,3,0,1]=0x4E,
//   xor4 -> row_half_mirror=0x141, xor8 -> row_mirror=0x140
// (bitwise-identical: before each mirror stage all source lanes of a group
// hold identical partials). Cross-16: v_readlane lanes 0/16/32/48 + pairwise
// combine = same tree order as xor16/xor32. Remaining bpermutes: 8/wave.
// Everything else byte-identical to verified R7 (44.3us, absmax 0).

#define DPP_ADD_F(v, C) \
    { (v) += __int_as_float(__builtin_amdgcn_update_dpp( \
        __float_as_int(v), __float_as_int(v), (C), 0xF, 0xF, 0)); }
#define DPP_MAX_F(v, C) \
    { (v) = fmaxf((v), __int_as_float(__builtin_amdgcn_update_dpp( \
        __float_as_int(v), __float_as_int(v), (C), 0xF, 0xF, 0))); }
#define DPP_RED16_ADD(v) \
    { DPP_ADD_F(v, 0xB1) DPP_ADD_F(v, 0x4E) DPP_ADD_F(v, 0x141) DPP_ADD_F(v, 0x140) }
#define DPP_RED16_MAX(v) \
    { DPP_MAX_F(v, 0xB1) DPP_MAX_F(v, 0x4E) DPP_MAX_F(v, 0x141) DPP_MAX_F(v, 0x140) }
#define RDLANE_F(v, l) __int_as_float(__builtin_amdgcn_readlane(__float_as_int(v), (l)))

__global__ void AGREE_12773232738622_probe(
    const void* member_mask,            // [8192, 50] unknown element width
    const void* user_table,             // [100000, 64] f32 or bf16
    int* ws)                            // ws[0]=width (1/2/4/8), ws[1]=isf32, ws[2]=done
{
    if (ws[2] == 0x5AFE0001) return;    // sticky: skip on graph replays if ws persists

    const int lane = threadIdx.x;       // 64 lanes
    const int wi = lane >> 4;           // candidate width index 0..3 (W = 1<<wi)
    const int r  = lane & 15;           // sample row 0..15 for this width

    int len = 0, ok = 1, prev = 1;
    for (int m = 0; m < 50; ++m) {
        long e = 50L * r + m;
        int nz;
        if (wi == 0)      nz = (((const unsigned char*)member_mask)[e] != 0);
        else if (wi == 1) nz = (((const unsigned short*)member_mask)[e] != 0);
        else if (wi == 2) nz = (((const unsigned int*)member_mask)[e] != 0u);
        else {
            const unsigned int* p = (const unsigned int*)member_mask;
            nz = ((p[2 * e] | p[2 * e + 1]) != 0u);
        }
        if (nz && !prev) ok = 0;        // gap -> not a prefix -> wrong width
        if (nz) len = len + 1;
        prev = nz;
    }
    if (len == 0) ok = 0;

    ok = ok & __shfl_xor(ok, 1);
    ok = ok & __shfl_xor(ok, 2);
    ok = ok & __shfl_xor(ok, 4);
    ok = ok & __shfl_xor(ok, 8);
    int mx = len;
    mx = max(mx, __shfl_xor(mx, 1));
    mx = max(mx, __shfl_xor(mx, 2));
    mx = max(mx, __shfl_xor(mx, 4));
    mx = max(mx, __shfl_xor(mx, 8));

    int o0 = __shfl(ok, 0),  o1 = __shfl(ok, 16), o2 = __shfl(ok, 32), o3 = __shfl(ok, 48);
    int L0 = __shfl(mx, 0),  L1 = __shfl(mx, 16), L2 = __shfl(mx, 32), L3 = __shfl(mx, 48);

    float v = __bfloat162float(((const __hip_bfloat16*)user_table)[lane]);
    float a = (v < 0.0f) ? -v : v;
    int huge = (!(a < 4.0f)) ? 1 : 0;
    unsigned long long hb = __ballot(huge);
    int hcnt = __popcll(hb);

    if (lane == 0) {
        int bestW = 1, bestLen = -1;
        if (o0 && L0 > bestLen) { bestLen = L0; bestW = 1; }
        if (o1 && L1 > bestLen) { bestLen = L1; bestW = 2; }
        if (o2 && L2 > bestLen) { bestLen = L2; bestW = 4; }
        if (o3 && L3 > bestLen) { bestLen = L3; bestW = 8; }
        ws[0] = bestW;
        ws[1] = (hcnt >= 8) ? 1 : 0;
        ws[2] = 0x5AFE0001;
    }
}

__global__ __launch_bounds__(256, 4) void AGREE_12773232738622_kernel(
    const int* member_idx,              // [8192, 50] int32
    const void* member_mask,            // [8192, 50] width in ws[0]
    const int* item_inputs,             // [8192] int32
    const void* user_table,             // [100000, 64]
    const void* item_table,             // [50000, 64]
    const void* att_w1,                 // [128, 16]
    const void* att_b1,                 // [16]
    const void* att_w2,                 // [16, 1]
    const void* att_b2,                 // [1]
    const void* pred_w1,                // [192, 8]
    const void* pred_b1,                // [8]
    const void* pred_w2,                // [8, 1]
    const void* pred_b2,                // [1]
    void* out,                          // [8192] (dtype follows ws[1])
    const int* ws)
{
    using s16x8 = __attribute__((ext_vector_type(8))) short;   // 8 bf16 raw
    using bf16x8 = __attribute__((ext_vector_type(8))) __bf16;
    using f32x4 = __attribute__((ext_vector_type(4))) float;

    __shared__ float s_l[4][64];        // per-wave logit transpose scratch
    __shared__ float s_g[4][64];        // per-wave pooled-g transpose scratch

    const int tid  = threadIdx.x;
    const int lane = tid & 63;
    const int wave = tid >> 6;
    const int b    = blockIdx.x * 4 + wave;   // one row per wave, 4 waves/block
    const int mode = ws[0];
    const int isf  = ws[1];

    // ---- mask: one element per lane, prefix length via ballot ----
    int valid = 0;
    if (lane < 50) {
        long e0 = 50L * b + lane;
        if (mode == 1)      valid = (((const unsigned char*)member_mask)[e0] != 0);
        else if (mode == 2) valid = (((const unsigned short*)member_mask)[e0] != 0);
        else if (mode == 4) valid = (((const unsigned int*)member_mask)[e0] != 0u);
        else {
            const unsigned int* p = (const unsigned int*)member_mask;
            valid = ((p[2 * e0] | p[2 * e0 + 1]) != 0u);
        }
    }
    unsigned long long vm = __ballot(valid);
    int len = __popcll(vm);
    if (len < 1)  len = 1;              // unreachable if probe is right
    if (len > 50) len = 50;

    const int item_id = item_inputs[b];
    int idxv = 0;
    if (lane < 50) idxv = member_idx[b * 50 + lane];

    if (!isf) {
        // ================= bf16 MFMA path =================
        const unsigned short* utp = (const unsigned short*)user_table;
        const unsigned short* w1p = (const unsigned short*)att_w1;

        // item embedding (lane = dim) for pred MLP
        const float itemv = __uint_as_float(
            (unsigned int)((const unsigned short*)item_table)[item_id * 64 + lane] << 16);

        // ---- B fragments: bfrag[kc] lane holds w1[kc*32+(l>>4)*8+j][l&15] ----
        const int kn = lane & 15;       // N index (hidden k)
        const int kg = lane >> 4;       // K group
        s16x8 bfrag[4];
        #pragma unroll
        for (int kc = 0; kc < 4; ++kc) {
            #pragma unroll
            for (int j = 0; j < 8; ++j)
                bfrag[kc][j] = (short)w1p[(kc * 32 + kg * 8 + j) * 16 + kn];
        }

        // ---- A fragments: afrag[t][ks] lane holds mem[t*16+(l&15)][ks*32+kg*8+j] ----
        s16x8 afrag[4][2];
        #pragma unroll
        for (int t = 0; t < 4; ++t) {
            int m  = t * 16 + (lane & 15);
            int mc = (m < 50) ? m : 0;                  // pad rows -> member 0 (finite, masked)
            int id = __shfl(idxv, mc);
            const unsigned short* rp = utp + (long)id * 64 + kg * 8;
            afrag[t][0] = *(const s16x8*)(rp);
            afrag[t][1] = *(const s16x8*)(rp + 32);
        }
        // item feature chunks (global k 64..127), identical for all rows
        const unsigned short* ipp = (const unsigned short*)item_table + (long)item_id * 64 + kg * 8;
        s16x8 ifrag0 = *(const s16x8*)(ipp);
        s16x8 ifrag1 = *(const s16x8*)(ipp + 32);

        // ---- 16 MFMA: h[m][k] for all 64 rows x 16 hidden, K=128 concat ----
        f32x4 acc[4];
        #pragma unroll
        for (int t = 0; t < 4; ++t) acc[t] = f32x4{0.0f, 0.0f, 0.0f, 0.0f};
        #pragma unroll
        for (int t = 0; t < 4; ++t) {
            acc[t] = __builtin_amdgcn_mfma_f32_16x16x32_bf16(
                __builtin_bit_cast(bf16x8, afrag[t][0]), __builtin_bit_cast(bf16x8, bfrag[0]), acc[t], 0, 0, 0);
            acc[t] = __builtin_amdgcn_mfma_f32_16x16x32_bf16(
                __builtin_bit_cast(bf16x8, afrag[t][1]), __builtin_bit_cast(bf16x8, bfrag[1]), acc[t], 0, 0, 0);
            acc[t] = __builtin_amdgcn_mfma_f32_16x16x32_bf16(
                __builtin_bit_cast(bf16x8, ifrag0),     __builtin_bit_cast(bf16x8, bfrag[2]), acc[t], 0, 0, 0);
            acc[t] = __builtin_amdgcn_mfma_f32_16x16x32_bf16(
                __builtin_bit_cast(bf16x8, ifrag1),     __builtin_bit_cast(bf16x8, bfrag[3]), acc[t], 0, 0, 0);
        }

        // ---- epilogue: logit_m = b2 + sum_k relu(h+b1)*w2; DPP reduce over kn ----
        const float b1v = __uint_as_float((unsigned int)((const unsigned short*)att_b1)[kn] << 16);
        const float w2v = __uint_as_float((unsigned int)((const unsigned short*)att_w2)[kn] << 16);
        const float b2v = __uint_as_float((unsigned int)((const unsigned short*)att_b2)[0] << 16);
        #pragma unroll
        for (int t = 0; t < 4; ++t) {
            #pragma unroll
            for (int r = 0; r < 4; ++r) {
                float v = fmaxf(acc[t][r] + b1v, 0.0f) * w2v;
                DPP_RED16_ADD(v)
                // C/D layout: member m = t*16 + (lane>>4)*4 + r
                if ((lane & 15) == 0) s_l[wave][t * 16 + (lane >> 4) * 4 + r] = v;
            }
        }
        __syncthreads();                // logits visible across lanes

        float lg = (lane < 50) ? s_l[wave][lane] : 0.0f;

        // ---- masked softmax: DPP within-16, readlane combine across groups ----
        float x = valid ? (lg + b2v) : -3.0e38f;
        float mxv = x;
        DPP_RED16_MAX(mxv)
        float mxs = fmaxf(fmaxf(RDLANE_F(mxv, 0), RDLANE_F(mxv, 16)),
                          fmaxf(RDLANE_F(mxv, 32), RDLANE_F(mxv, 48)));
        float p = valid ? expf(x - mxs) : 0.0f;
        float sum = p;
        DPP_RED16_ADD(sum)
        float sums = (RDLANE_F(sum, 0) + RDLANE_F(sum, 16))
                   + (RDLANE_F(sum, 32) + RDLANE_F(sum, 48));
        float wnorm;
        if (sums > 0.0f) wnorm = p * (1.0f / sums);
        else             wnorm = (lane == 0) ? 1.0f : 0.0f;  // structural NaN guard

        // ---- pooling from the A-fragments already in registers ----
        // lane l holds mem[t*16+(l&15)][d], d = ks*32 + kg*8 + j
        float pg[2][8];
        #pragma unroll
        for (int ks = 0; ks < 2; ++ks)
            #pragma unroll
            for (int j = 0; j < 8; ++j) pg[ks][j] = 0.0f;
        #pragma unroll
        for (int t = 0; t < 4; ++t) {
            float wv = __shfl(wnorm, t * 16 + (lane & 15));  // wt of member t*16+(l&15); 0 for pads
            #pragma unroll
            for (int ks = 0; ks < 2; ++ks) {
                #pragma unroll
                for (int j = 0; j < 8; ++j) {
                    float e = __uint_as_float(
                        (unsigned int)(unsigned short)afrag[t][ks][j] << 16);
                    pg[ks][j] += wv * e;
                }
            }
        }
        // reduce over the 16 lanes (member axis) within each k-group: DPP
        #pragma unroll
        for (int ks = 0; ks < 2; ++ks) {
            #pragma unroll
            for (int j = 0; j < 8; ++j) {
                DPP_RED16_ADD(pg[ks][j])
            }
        }
        if ((lane & 15) == 0) {
            #pragma unroll
            for (int ks = 0; ks < 2; ++ks)
                #pragma unroll
                for (int j = 0; j < 8; ++j)
                    s_g[wave][ks * 32 + (lane >> 4) * 8 + j] = pg[ks][j];
        }
        __syncthreads();                // pooled g visible, lane = dim
        const float g = s_g[wave][lane];

        // ---- prediction MLP: new = [g*item, g, item]; coalesced bf16 loads ----
        const float gi = g * itemv;
        const uint4* pw4 = (const uint4*)pred_w1;     // row r = pw4[r] (8 bf16 = 16B)
        uint4 A = pw4[lane];
        uint4 Bv = pw4[64 + lane];
        uint4 C = pw4[128 + lane];
        float ea[8], eb[8], ec[8];
        ea[0] = __uint_as_float(A.x << 16);  ea[1] = __uint_as_float(A.x & 0xFFFF0000u);
        ea[2] = __uint_as_float(A.y << 16);  ea[3] = __uint_as_float(A.y & 0xFFFF0000u);
        ea[4] = __uint_as_float(A.z << 16);  ea[5] = __uint_as_float(A.z & 0xFFFF0000u);
        ea[6] = __uint_as_float(A.w << 16);  ea[7] = __uint_as_float(A.w & 0xFFFF0000u);
        eb[0] = __uint_as_float(Bv.x << 16); eb[1] = __uint_as_float(Bv.x & 0xFFFF0000u);
        eb[2] = __uint_as_float(Bv.y << 16); eb[3] = __uint_as_float(Bv.y & 0xFFFF0000u);
        eb[4] = __uint_as_float(Bv.z << 16); eb[5] = __uint_as_float(Bv.z & 0xFFFF0000u);
        eb[6] = __uint_as_float(Bv.w << 16); eb[7] = __uint_as_float(Bv.w & 0xFFFF0000u);
        ec[0] = __uint_as_float(C.x << 16);  ec[1] = __uint_as_float(C.x & 0xFFFF0000u);
        ec[2] = __uint_as_float(C.y << 16);  ec[3] = __uint_as_float(C.y & 0xFFFF0000u);
        ec[4] = __uint_as_float(C.z << 16);  ec[5] = __uint_as_float(C.z & 0xFFFF0000u);
        ec[6] = __uint_as_float(C.w << 16);  ec[7] = __uint_as_float(C.w & 0xFFFF0000u);
        float p8[8];
        #pragma unroll
        for (int k2 = 0; k2 < 8; ++k2)
            p8[k2] = gi * ea[k2] + g * eb[k2] + itemv * ec[k2];
        #pragma unroll
        for (int k2 = 0; k2 < 8; ++k2) {
            float v = p8[k2];
            DPP_RED16_ADD(v)
            p8[k2] = (RDLANE_F(v, 0) + RDLANE_F(v, 16))
                   + (RDLANE_F(v, 32) + RDLANE_F(v, 48));
        }
        if (lane == 0) {
            float z = __uint_as_float((unsigned int)((const unsigned short*)pred_b2)[0] << 16);
            for (int k2 = 0; k2 < 8; ++k2) {
                float bb2 = __uint_as_float((unsigned int)((const unsigned short*)pred_b1)[k2] << 16);
                float ww  = __uint_as_float((unsigned int)((const unsigned short*)pred_w2)[k2] << 16);
                float hh = p8[k2] + bb2;
                if (hh < 0.0f) hh = 0.0f;
                z += hh * ww;
            }
            float y = 1.0f / (1.0f + expf(-z));
            ((__hip_bfloat16*)out)[b] = __float2bfloat16(y);
        }
    } else {
        // ================= f32 fallback (round-10 verified structure) =================
        const float itemv = ((const float*)item_table)[item_id * 64 + lane];

        float part;
        {
            const int kk = lane & 15;
            const int c  = lane >> 4;
            part = (c == 0) ? ((const float*)att_b1)[kk] : 0.0f;
            for (int t = 0; t < 16; ++t) {
                int f = c * 16 + t;
                float iv = __shfl(itemv, f);
                part += iv * ((const float*)att_w1)[(64 + f) * 16 + kk];
            }
            part += __shfl_xor(part, 16);
            part += __shfl_xor(part, 32);
        }
        float h[16];
        #pragma unroll
        for (int k = 0; k < 16; ++k) h[k] = __shfl(part, k);

        if (lane < len) {
            const float* rp = (const float*)user_table + (long)idxv * 64;
            const float* w1 = (const float*)att_w1;
            #pragma unroll 4
            for (int c = 0; c < 16; ++c) {
                float4 v = ((const float4*)rp)[c];
                #pragma unroll
                for (int k = 0; k < 16; ++k) {
                    h[k] += v.x * w1[(c * 4 + 0) * 16 + k];
                    h[k] += v.y * w1[(c * 4 + 1) * 16 + k];
                    h[k] += v.z * w1[(c * 4 + 2) * 16 + k];
                    h[k] += v.w * w1[(c * 4 + 3) * 16 + k];
                }
            }
        }

        float lg = ((const float*)att_b2)[0];
        #pragma unroll
        for (int k = 0; k < 16; ++k)
            lg += fmaxf(h[k], 0.0f) * ((const float*)att_w2)[k];

        float x = valid ? lg : -3.0e38f;
        float mxv = x;
        mxv = fmaxf(mxv, __shfl_xor(mxv, 1));
        mxv = fmaxf(mxv, __shfl_xor(mxv, 2));
        mxv = fmaxf(mxv, __shfl_xor(mxv, 4));
        mxv = fmaxf(mxv, __shfl_xor(mxv, 8));
        mxv = fmaxf(mxv, __shfl_xor(mxv, 16));
        mxv = fmaxf(mxv, __shfl_xor(mxv, 32));
        float p = valid ? expf(x - mxv) : 0.0f;
        float sum = p;
        sum += __shfl_xor(sum, 1);
        sum += __shfl_xor(sum, 2);
        sum += __shfl_xor(sum, 4);
        sum += __shfl_xor(sum, 8);
        sum += __shfl_xor(sum, 16);
        sum += __shfl_xor(sum, 32);
        float wnorm;
        if (sum > 0.0f) wnorm = p * (1.0f / sum);
        else            wnorm = (lane == 0) ? 1.0f : 0.0f;

        float g = 0.0f;
        const float* ut = (const float*)user_table;
        for (int m = 0; m < len; ++m) {
            int idm  = __shfl(idxv, m);
            float wv = __shfl(wnorm, m);
            g += wv * ut[(long)idm * 64 + lane];
        }

        const float gi = g * itemv;
        const float4* pw4 = (const float4*)pred_w1;
        float4 a0 = pw4[lane * 2],         a1 = pw4[lane * 2 + 1];
        float4 b0 = pw4[(64 + lane) * 2],  b1 = pw4[(64 + lane) * 2 + 1];
        float4 c0 = pw4[(128 + lane) * 2], c1 = pw4[(128 + lane) * 2 + 1];
        float p8[8];
        p8[0] = gi * a0.x + g * b0.x + itemv * c0.x;
        p8[1] = gi * a0.y + g * b0.y + itemv * c0.y;
        p8[2] = gi * a0.z + g * b0.z + itemv * c0.z;
        p8[3] = gi * a0.w + g * b0.w + itemv * c0.w;
        p8[4] = gi * a1.x + g * b1.x + itemv * c1.x;
        p8[5] = gi * a1.y + g * b1.y + itemv * c1.y;
        p8[6] = gi * a1.z + g * b1.z + itemv * c1.z;
        p8[7] = gi * a1.w + g * b1.w + itemv * c1.w;
        #pragma unroll
        for (int k2 = 0; k2 < 8; ++k2) {
            float v = p8[k2];
            v += __shfl_xor(v, 1);
            v += __shfl_xor(v, 2);
            v += __shfl_xor(v, 4);
            v += __shfl_xor(v, 8);
            v += __shfl_xor(v, 16);
            v += __shfl_xor(v, 32);
            p8[k2] = v;
        }
        if (lane == 0) {
            float z = ((const float*)pred_b2)[0];
            for (int k2 = 0; k2 < 8; ++k2) {
                float hh = p8[k2] + ((const float*)pred_b1)[k2];
                if (hh < 0.0f) hh = 0.0f;
                z += hh * ((const float*)pred_w2)[k2];
            }
            float y = 1.0f / (1.0f + expf(-z));
            ((float*)out)[b] = y;
        }
    }
}

extern "C" void kernel_launch(void* const* d_in, const int* in_sizes, int n_in,
                              void* d_out, int out_size, void* d_ws, size_t ws_size,
                              hipStream_t stream) {
    (void)in_sizes; (void)n_in; (void)out_size; (void)ws_size;
    AGREE_12773232738622_probe<<<1, 64, 0, stream>>>(
        d_in[1], d_in[3], (int*)d_ws);
    AGREE_12773232738622_kernel<<<2048, 256, 0, stream>>>(
        (const int*)d_in[0],
        d_in[1],
        (const int*)d_in[2],
        d_in[3],
        d_in[4],
        d_in[5],
        d_in[6],
        d_in[7],
        d_in[8],
        d_in[9],
        d_in[10],
        d_in[11],
        d_in[12],
        d_out,
        (const int*)d_ws);
}